// Round 3
// baseline (192.988 us; speedup 1.0000x reference)
//
#include <hip/hip_runtime.h>

#define B_SZ 4096
#define N_IN 4096
#define N_CTX 512
#define UNITS 4096
#define RANK 256
#define ZSPLIT 16

typedef __attribute__((ext_vector_type(8))) __bf16 bf16x8;
typedef __attribute__((ext_vector_type(4))) float f32x4;
typedef __attribute__((ext_vector_type(8))) unsigned short ushort8;

// RNE f32->bf16 via native cast: compiler emits v_cvt_pk_bf16_f32 (1 op / 2 elems)
__device__ __forceinline__ unsigned short f2bf(float f) {
    __bf16 h = (__bf16)f;
    return __builtin_bit_cast(unsigned short, h);
}
__device__ __forceinline__ float bf2f(unsigned short h) {
    return __uint_as_float(((unsigned int)h) << 16);
}
__device__ __forceinline__ void gload_lds16(const unsigned short* g, unsigned short* l) {
    __builtin_amdgcn_global_load_lds(
        (const __attribute__((address_space(1))) unsigned int*)g,
        (__attribute__((address_space(3))) unsigned int*)l, 16, 0, 0);
}
__device__ __forceinline__ bf16x8 ldfrag(const unsigned short* p) {
    ushort8 t = *(const ushort8*)p;
    return __builtin_bit_cast(bf16x8, t);
}

// ---- fused prep: U^T, W^T transposes + V convert + X convert, one launch ----
// grid: 256 (U) + 32 (W) + 512 (V, 2048 elem/blk) + 4096 (X, 4096 elem/blk) = 4896
__global__ void prep(const float* __restrict__ U, const float* __restrict__ W,
                     const float* __restrict__ V, const float* __restrict__ X,
                     unsigned short* __restrict__ UT, unsigned short* __restrict__ WT,
                     unsigned short* __restrict__ Vb, unsigned short* __restrict__ Xb) {
    __shared__ unsigned short t[64][66];
    int bid = blockIdx.x, tid = threadIdx.x;
    if (bid < 288) {
        const float* src; unsigned short* dst; int R, C, rb, cb;
        if (bid < 256) { src = U; dst = UT; R = N_IN; C = RANK; rb = (bid & 63) * 64; cb = (bid >> 6) * 64; }
        else { int b = bid - 256; src = W; dst = WT; R = N_CTX; C = RANK; rb = (b & 7) * 64; cb = (b >> 3) * 64; }
        int r = tid >> 4, c4 = (tid & 15) * 4;
        for (int i = 0; i < 4; i++) {
            float4 v = *(const float4*)(src + (size_t)(rb + r + i * 16) * C + cb + c4);
            t[r + i * 16][c4 + 0] = f2bf(v.x);
            t[r + i * 16][c4 + 1] = f2bf(v.y);
            t[r + i * 16][c4 + 2] = f2bf(v.z);
            t[r + i * 16][c4 + 3] = f2bf(v.w);
        }
        __syncthreads();
        int c = tid >> 3, r8 = (tid & 7) * 8;
        for (int j = 0; j < 2; j++) {
            int cc = c + j * 32;
            ushort8 o;
            for (int k = 0; k < 8; k++) o[k] = t[r8 + k][cc];
            *(ushort8*)(dst + (size_t)(cb + cc) * R + rb + r8) = o;
        }
    } else if (bid < 800) {
        size_t base = (size_t)(bid - 288) * 2048 + (size_t)tid * 8;
        float4 a = *(const float4*)(V + base);
        float4 b = *(const float4*)(V + base + 4);
        ushort8 o = { f2bf(a.x), f2bf(a.y), f2bf(a.z), f2bf(a.w),
                      f2bf(b.x), f2bf(b.y), f2bf(b.z), f2bf(b.w) };
        *(ushort8*)(Vb + base) = o;
    } else {
        size_t base = (size_t)(bid - 800) * 4096 + (size_t)tid * 16;
        float4 a = *(const float4*)(X + base);
        float4 b = *(const float4*)(X + base + 4);
        float4 c = *(const float4*)(X + base + 8);
        float4 d = *(const float4*)(X + base + 12);
        ushort8 o0 = { f2bf(a.x), f2bf(a.y), f2bf(a.z), f2bf(a.w),
                       f2bf(b.x), f2bf(b.y), f2bf(b.z), f2bf(b.w) };
        ushort8 o1 = { f2bf(c.x), f2bf(c.y), f2bf(c.z), f2bf(c.w),
                       f2bf(d.x), f2bf(d.y), f2bf(d.z), f2bf(d.w) };
        *(ushort8*)(Xb + base) = o0;
        *(ushort8*)(Xb + base + 8) = o1;
    }
}

// All GEMM tiles: rows of 64 bf16 = 128B = 8 chunks of 16B.
// LDS slot (row, cs) holds data chunk cs^(row&7)  -> bank-balanced b128 access.

// ---- K1: Schi = S * sigmoid(context@W + B), bf16 out ------------------
// tile 32x64, BK=64, grid (4,128) = 512 blocks
__launch_bounds__(256, 4)
__global__ void k1_chi(const float* __restrict__ ctx, const unsigned short* __restrict__ WT,
                       const float* __restrict__ S, const float* __restrict__ Bb,
                       unsigned short* __restrict__ Schi) {
    __shared__ unsigned short As[32 * 64];
    __shared__ unsigned short Bs[64 * 64];
    int tid = threadIdx.x, w = tid >> 6, lane = tid & 63;
    int ln15 = lane & 15, quad = lane >> 4;
    int wr = w >> 1, wc = w & 1;
    int tm = blockIdx.y * 32, tn = blockIdx.x * 64;
    f32x4 acc2[2] = {};
    int arow = tid >> 3, acs = tid & 7;                 // A: 1 chunk/thread
    const float* ag = ctx + (size_t)(tm + arow) * N_CTX + acs * 8;
    unsigned short* al = As + arow * 64 + (acs ^ (arow & 7)) * 8;
    int bl8 = lane >> 3, bcs = lane & 7;
    int bgc = (bcs ^ bl8) * 8;                          // swizzled global chunk for B
    for (int kt = 0; kt < 8; kt++) {
        int k0 = kt * 64;
        for (int c = 0; c < 2; c++) {
            int row = w * 16 + c * 8 + bl8;
            gload_lds16(WT + (size_t)(tn + row) * N_CTX + k0 + bgc, Bs + row * 64 + bcs * 8);
        }
        {
            float4 v0 = *(const float4*)(ag + k0);
            float4 v1 = *(const float4*)(ag + k0 + 4);
            ushort8 a8 = { f2bf(v0.x), f2bf(v0.y), f2bf(v0.z), f2bf(v0.w),
                           f2bf(v1.x), f2bf(v1.y), f2bf(v1.z), f2bf(v1.w) };
            *(ushort8*)al = a8;
        }
        __syncthreads();
        for (int kh = 0; kh < 2; kh++) {
            int ch = kh * 4 + quad;
            bf16x8 af = ldfrag(As + (wr * 16 + ln15) * 64 + (ch ^ (ln15 & 7)) * 8);
            for (int j = 0; j < 2; j++) {
                int row = wc * 32 + j * 16 + ln15;
                bf16x8 bfr = ldfrag(Bs + row * 64 + (ch ^ (ln15 & 7)) * 8);
                acc2[j] = __builtin_amdgcn_mfma_f32_16x16x32_bf16(af, bfr, acc2[j], 0, 0, 0);
            }
        }
        __syncthreads();
    }
    for (int j = 0; j < 2; j++) {
        int col = tn + wc * 32 + j * 16 + ln15;
        float sv = S[col], bv = Bb[col];
        for (int r = 0; r < 4; r++) {
            int row = tm + wr * 16 + quad * 4 + r;
            float x = acc2[j][r] + bv;
            float chi = sv / (1.f + __expf(-x));
            Schi[(size_t)row * RANK + col] = f2bf(chi);
        }
    }
}

// ---- K2: T0p[z] = Xb@U partial (split-K, bf16 partials) ---------------
// m97 geometry: tile 128x128, BK=64 (4 steps), both operands global_load_lds,
// 32KB LDS single-buffer, grid (2, 32, 16) = 1024 blocks
__launch_bounds__(256, 3)
__global__ void k2_t0(const unsigned short* __restrict__ Xb, const unsigned short* __restrict__ UT,
                      unsigned short* __restrict__ T0p) {
    __shared__ unsigned short As[128 * 64];
    __shared__ unsigned short Bs[128 * 64];
    int tid = threadIdx.x, w = tid >> 6, lane = tid & 63;
    int ln15 = lane & 15, quad = lane >> 4;
    int wr = w >> 1, wc = w & 1;
    int tm = blockIdx.y * 128, tn = blockIdx.x * 128;
    int kbase = blockIdx.z * (N_IN / ZSPLIT);
    f32x4 acc[4][4] = {};
    int bl8 = lane >> 3, bcs = lane & 7;
    int bgc = (bcs ^ bl8) * 8;
    for (int kt = 0; kt < (N_IN / ZSPLIT) / 64; kt++) {
        int k0 = kt * 64;
        for (int c = 0; c < 4; c++) {
            int row = w * 32 + c * 8 + bl8;
            gload_lds16(Xb + (size_t)(tm + row) * N_IN + kbase + k0 + bgc, As + row * 64 + bcs * 8);
            gload_lds16(UT + (size_t)(tn + row) * N_IN + kbase + k0 + bgc, Bs + row * 64 + bcs * 8);
        }
        __syncthreads();
        for (int kh = 0; kh < 2; kh++) {
            int ch = kh * 4 + quad;
            int sw = (ch ^ (ln15 & 7)) * 8;
            bf16x8 af[4], bfr[4];
            for (int i = 0; i < 4; i++)
                af[i] = ldfrag(As + (wr * 64 + i * 16 + ln15) * 64 + sw);
            for (int j = 0; j < 4; j++)
                bfr[j] = ldfrag(Bs + (wc * 64 + j * 16 + ln15) * 64 + sw);
            for (int i = 0; i < 4; i++)
                for (int j = 0; j < 4; j++)
                    acc[i][j] = __builtin_amdgcn_mfma_f32_16x16x32_bf16(af[i], bfr[j], acc[i][j], 0, 0, 0);
        }
        __syncthreads();
    }
    unsigned short* P = T0p + (size_t)blockIdx.z * B_SZ * RANK;
    for (int j = 0; j < 4; j++) {
        int col = tn + wc * 64 + j * 16 + ln15;
        for (int i = 0; i < 4; i++)
            for (int r = 0; r < 4; r++) {
                int row = tm + wr * 64 + i * 16 + quad * 4 + r;
                P[(size_t)row * RANK + col] = f2bf(acc[i][j][r]);
            }
    }
}

// ---- E: T = bf16( (sum_z T0p[z]) * Schi ) ------------------------------
__global__ void e_red(const unsigned short* __restrict__ T0p, const unsigned short* __restrict__ Schi,
                      unsigned short* __restrict__ T) {
    int i = blockIdx.x * 256 + threadIdx.x;   // ushort8 index
    const size_t stride = (size_t)B_SZ * RANK;
    float a[8] = {};
    for (int z = 0; z < ZSPLIT; z++) {
        ushort8 p = *(const ushort8*)(T0p + z * stride + (size_t)i * 8);
        for (int k = 0; k < 8; k++) a[k] += bf2f(p[k]);
    }
    ushort8 s = *(const ushort8*)(Schi + (size_t)i * 8);
    ushort8 o;
    for (int k = 0; k < 8; k++) o[k] = f2bf(a[k] * bf2f(s[k]));
    *(ushort8*)(T + (size_t)i * 8) = o;
}

// ---- K3: out = relu(T @ V^T + 2*bias) ---------------------------------
// tile 128x128 (m x n), BK=64 (4 iters), grid (32, 32) = 1024 blocks
__launch_bounds__(256, 3)
__global__ void k3_out(const unsigned short* __restrict__ T, const unsigned short* __restrict__ Vb,
                       const float* __restrict__ bias, float* __restrict__ out) {
    __shared__ unsigned short As[128 * 64];
    __shared__ unsigned short Bs[128 * 64];
    int tid = threadIdx.x, w = tid >> 6, lane = tid & 63;
    int ln15 = lane & 15, quad = lane >> 4;
    int wr = w >> 1, wc = w & 1;
    int tn = blockIdx.x * 128, tm = blockIdx.y * 128;
    f32x4 acc[4][4] = {};
    int bl8 = lane >> 3, bcs = lane & 7;
    int bgc = (bcs ^ bl8) * 8;
    for (int kt = 0; kt < RANK / 64; kt++) {
        int k0 = kt * 64;
        for (int c = 0; c < 4; c++) {
            int row = w * 32 + c * 8 + bl8;
            gload_lds16(T + (size_t)(tm + row) * RANK + k0 + bgc, As + row * 64 + bcs * 8);
            gload_lds16(Vb + (size_t)(tn + row) * RANK + k0 + bgc, Bs + row * 64 + bcs * 8);
        }
        __syncthreads();
        for (int kh = 0; kh < 2; kh++) {
            int ch = kh * 4 + quad;
            int sw = (ch ^ (ln15 & 7)) * 8;
            bf16x8 af[4], bfr[4];
            for (int i = 0; i < 4; i++)
                af[i] = ldfrag(As + (wr * 64 + i * 16 + ln15) * 64 + sw);
            for (int j = 0; j < 4; j++)
                bfr[j] = ldfrag(Bs + (wc * 64 + j * 16 + ln15) * 64 + sw);
            for (int i = 0; i < 4; i++)
                for (int j = 0; j < 4; j++)
                    acc[i][j] = __builtin_amdgcn_mfma_f32_16x16x32_bf16(af[i], bfr[j], acc[i][j], 0, 0, 0);
        }
        __syncthreads();
    }
    for (int j = 0; j < 4; j++) {
        int col = tn + wc * 64 + j * 16 + ln15;
        float bv = 2.f * bias[col];
        for (int i = 0; i < 4; i++)
            for (int r = 0; r < 4; r++) {
                int row = tm + wr * 64 + i * 16 + quad * 4 + r;
                float v = acc[i][j][r] + bv;
                out[(size_t)row * UNITS + col] = fmaxf(v, 0.f);
            }
    }
}

extern "C" void kernel_launch(void* const* d_in, const int* in_sizes, int n_in,
                              void* d_out, int out_size, void* d_ws, size_t ws_size,
                              hipStream_t stream) {
    (void)in_sizes; (void)n_in; (void)out_size; (void)ws_size;
    const float* inputs  = (const float*)d_in[0];
    const float* context = (const float*)d_in[1];
    const float* U       = (const float*)d_in[2];
    const float* S       = (const float*)d_in[3];
    const float* V       = (const float*)d_in[4];
    const float* W       = (const float*)d_in[5];
    const float* Bb      = (const float*)d_in[6];
    const float* bias    = (const float*)d_in[7];
    float* out = (float*)d_out;

    char* ws = (char*)d_ws;
    size_t o = 0;
    unsigned short* UT   = (unsigned short*)(ws + o); o += (size_t)RANK * N_IN * 2;
    unsigned short* WT   = (unsigned short*)(ws + o); o += (size_t)RANK * N_CTX * 2;
    unsigned short* Vb   = (unsigned short*)(ws + o); o += (size_t)UNITS * RANK * 2;
    unsigned short* Xb   = (unsigned short*)(ws + o); o += (size_t)B_SZ * N_IN * 2;
    unsigned short* Schi = (unsigned short*)(ws + o); o += (size_t)B_SZ * RANK * 2;
    unsigned short* T    = (unsigned short*)(ws + o); o += (size_t)B_SZ * RANK * 2;
    unsigned short* T0p  = (unsigned short*)(ws + o); o += (size_t)ZSPLIT * B_SZ * RANK * 2;

    prep<<<4896, 256, 0, stream>>>(U, W, V, inputs, UT, WT, Vb, Xb);
    k2_t0<<<dim3(RANK / 128, B_SZ / 128, ZSPLIT), 256, 0, stream>>>(Xb, UT, T0p);
    k1_chi<<<dim3(RANK / 64, B_SZ / 32), 256, 0, stream>>>(context, WT, S, Bb, Schi);
    e_red<<<(B_SZ * RANK) / (256 * 8), 256, 0, stream>>>(T0p, Schi, T);
    k3_out<<<dim3(UNITS / 128, B_SZ / 128), 256, 0, stream>>>(T, Vb, bias, out);
}

// Round 4
// 184.927 us; speedup vs baseline: 1.0436x; 1.0436x over previous
//
#include <hip/hip_runtime.h>

#define B_SZ 4096
#define N_IN 4096
#define N_CTX 512
#define UNITS 4096
#define RANK 256
#define ZSPLIT 16

typedef __attribute__((ext_vector_type(8))) __bf16 bf16x8;
typedef __attribute__((ext_vector_type(4))) float f32x4;
typedef __attribute__((ext_vector_type(8))) unsigned short ushort8;

// RNE f32->bf16 via native cast: compiler emits v_cvt_pk_bf16_f32 (1 op / 2 elems)
__device__ __forceinline__ unsigned short f2bf(float f) {
    __bf16 h = (__bf16)f;
    return __builtin_bit_cast(unsigned short, h);
}
__device__ __forceinline__ float bf2f(unsigned short h) {
    return __uint_as_float(((unsigned int)h) << 16);
}
__device__ __forceinline__ void gload_lds16(const unsigned short* g, unsigned short* l) {
    __builtin_amdgcn_global_load_lds(
        (const __attribute__((address_space(1))) unsigned int*)g,
        (__attribute__((address_space(3))) unsigned int*)l, 16, 0, 0);
}
__device__ __forceinline__ bf16x8 ldfrag(const unsigned short* p) {
    ushort8 t = *(const ushort8*)p;
    return __builtin_bit_cast(bf16x8, t);
}

// ---- fused prep: U^T (bf16), W^T (bf16), V convert (bf16), one launch ----
__global__ void prep(const float* __restrict__ U, const float* __restrict__ W,
                     const float* __restrict__ V,
                     unsigned short* __restrict__ UT, unsigned short* __restrict__ WT,
                     unsigned short* __restrict__ Vb) {
    __shared__ unsigned short t[64][66];
    int bid = blockIdx.x, tid = threadIdx.x;
    if (bid < 288) {
        const float* src; unsigned short* dst; int R, C, rb, cb;
        if (bid < 256) { src = U; dst = UT; R = N_IN; C = RANK; rb = (bid & 63) * 64; cb = (bid >> 6) * 64; }
        else { int b = bid - 256; src = W; dst = WT; R = N_CTX; C = RANK; rb = (b & 7) * 64; cb = (b >> 3) * 64; }
        int r = tid >> 4, c4 = (tid & 15) * 4;
        for (int i = 0; i < 4; i++) {
            float4 v = *(const float4*)(src + (size_t)(rb + r + i * 16) * C + cb + c4);
            t[r + i * 16][c4 + 0] = f2bf(v.x);
            t[r + i * 16][c4 + 1] = f2bf(v.y);
            t[r + i * 16][c4 + 2] = f2bf(v.z);
            t[r + i * 16][c4 + 3] = f2bf(v.w);
        }
        __syncthreads();
        int c = tid >> 3, r8 = (tid & 7) * 8;
        for (int j = 0; j < 2; j++) {
            int cc = c + j * 32;
            ushort8 o;
            for (int k = 0; k < 8; k++) o[k] = t[r8 + k][cc];
            *(ushort8*)(dst + (size_t)(cb + cc) * R + rb + r8) = o;
        }
    } else {
        size_t base = (size_t)(bid - 288) * 2048 + (size_t)tid * 8;
        float4 a = *(const float4*)(V + base);
        float4 b = *(const float4*)(V + base + 4);
        ushort8 o = { f2bf(a.x), f2bf(a.y), f2bf(a.z), f2bf(a.w),
                      f2bf(b.x), f2bf(b.y), f2bf(b.z), f2bf(b.w) };
        *(ushort8*)(Vb + base) = o;
    }
}

// All GEMM tiles: rows of 64 bf16 = 128B = 8 chunks of 16B.
// LDS slot (row, cs) holds data chunk cs^(row&7)  -> bank-balanced b128 access.

// ---- K1: Schi = S * sigmoid(context@W + B), bf16 out ------------------
// tile 32x64, BK=64, grid (4,128) = 512 blocks
__launch_bounds__(256, 4)
__global__ void k1_chi(const float* __restrict__ ctx, const unsigned short* __restrict__ WT,
                       const float* __restrict__ S, const float* __restrict__ Bb,
                       unsigned short* __restrict__ Schi) {
    __shared__ unsigned short As[32 * 64];
    __shared__ unsigned short Bs[64 * 64];
    int tid = threadIdx.x, w = tid >> 6, lane = tid & 63;
    int ln15 = lane & 15, quad = lane >> 4;
    int wr = w >> 1, wc = w & 1;
    int tm = blockIdx.y * 32, tn = blockIdx.x * 64;
    f32x4 acc2[2] = {};
    int arow = tid >> 3, acs = tid & 7;                 // A: 1 chunk/thread
    const float* ag = ctx + (size_t)(tm + arow) * N_CTX + acs * 8;
    unsigned short* al = As + arow * 64 + (acs ^ (arow & 7)) * 8;
    int bl8 = lane >> 3, bcs = lane & 7;
    int bgc = (bcs ^ bl8) * 8;                          // swizzled global chunk for B
    for (int kt = 0; kt < 8; kt++) {
        int k0 = kt * 64;
        for (int c = 0; c < 2; c++) {
            int row = w * 16 + c * 8 + bl8;
            gload_lds16(WT + (size_t)(tn + row) * N_CTX + k0 + bgc, Bs + row * 64 + bcs * 8);
        }
        {
            float4 v0 = *(const float4*)(ag + k0);
            float4 v1 = *(const float4*)(ag + k0 + 4);
            ushort8 a8 = { f2bf(v0.x), f2bf(v0.y), f2bf(v0.z), f2bf(v0.w),
                           f2bf(v1.x), f2bf(v1.y), f2bf(v1.z), f2bf(v1.w) };
            *(ushort8*)al = a8;
        }
        __syncthreads();
        for (int kh = 0; kh < 2; kh++) {
            int ch = kh * 4 + quad;
            bf16x8 af = ldfrag(As + (wr * 16 + ln15) * 64 + (ch ^ (ln15 & 7)) * 8);
            for (int j = 0; j < 2; j++) {
                int row = wc * 32 + j * 16 + ln15;
                bf16x8 bfr = ldfrag(Bs + row * 64 + (ch ^ (ln15 & 7)) * 8);
                acc2[j] = __builtin_amdgcn_mfma_f32_16x16x32_bf16(af, bfr, acc2[j], 0, 0, 0);
            }
        }
        __syncthreads();
    }
    for (int j = 0; j < 2; j++) {
        int col = tn + wc * 32 + j * 16 + ln15;
        float sv = S[col], bv = Bb[col];
        for (int r = 0; r < 4; r++) {
            int row = tm + wr * 16 + quad * 4 + r;
            float x = acc2[j][r] + bv;
            float chi = sv / (1.f + __expf(-x));
            Schi[(size_t)row * RANK + col] = f2bf(chi);
        }
    }
}

// ---- K2: T0p[z] = inputs@U partial (split-K, bf16 partials) -----------
// tile 64x256 (full RANK), BK=64, K-slice 256 (4 steps),
// grid (1, 64, 16) = 1024 blocks (~3 blocks/CU), 40KB LDS single-buffer
__launch_bounds__(256, 2)
__global__ void k2_t0(const float* __restrict__ X, const unsigned short* __restrict__ UT,
                      unsigned short* __restrict__ T0p) {
    __shared__ unsigned short As[64 * 64];
    __shared__ unsigned short Bs[256 * 64];
    int tid = threadIdx.x, w = tid >> 6, lane = tid & 63;
    int ln15 = lane & 15, quad = lane >> 4;
    int wr = w >> 1, wc = w & 1;
    int tm = blockIdx.y * 64;
    int kbase = blockIdx.z * (N_IN / ZSPLIT);
    f32x4 acc[2][8] = {};
    int arow = tid >> 2, acs0 = (tid & 3) * 2;          // A: 2 chunks/thread (16 f32)
    const float* ag = X + (size_t)(tm + arow) * N_IN + kbase + acs0 * 8;
    unsigned short* al0 = As + arow * 64 + ((acs0 + 0) ^ (arow & 7)) * 8;
    unsigned short* al1 = As + arow * 64 + ((acs0 + 1) ^ (arow & 7)) * 8;
    int bl8 = lane >> 3, bcs = lane & 7;
    int bgc = (bcs ^ bl8) * 8;
    for (int kt = 0; kt < (N_IN / ZSPLIT) / 64; kt++) {
        int k0 = kt * 64;
        for (int c = 0; c < 8; c++) {
            int row = w * 64 + c * 8 + bl8;             // rows 0..255 = full RANK
            gload_lds16(UT + (size_t)row * N_IN + kbase + k0 + bgc, Bs + row * 64 + bcs * 8);
        }
        {
            float4 v0 = *(const float4*)(ag + k0);
            float4 v1 = *(const float4*)(ag + k0 + 4);
            float4 u0 = *(const float4*)(ag + k0 + 8);
            float4 u1 = *(const float4*)(ag + k0 + 12);
            ushort8 a8 = { f2bf(v0.x), f2bf(v0.y), f2bf(v0.z), f2bf(v0.w),
                           f2bf(v1.x), f2bf(v1.y), f2bf(v1.z), f2bf(v1.w) };
            ushort8 b8 = { f2bf(u0.x), f2bf(u0.y), f2bf(u0.z), f2bf(u0.w),
                           f2bf(u1.x), f2bf(u1.y), f2bf(u1.z), f2bf(u1.w) };
            *(ushort8*)al0 = a8;
            *(ushort8*)al1 = b8;
        }
        __syncthreads();
        for (int kh = 0; kh < 2; kh++) {
            int ch = kh * 4 + quad;
            int sw = (ch ^ (ln15 & 7)) * 8;
            bf16x8 af0 = ldfrag(As + (wr * 32 + 0 * 16 + ln15) * 64 + sw);
            bf16x8 af1 = ldfrag(As + (wr * 32 + 1 * 16 + ln15) * 64 + sw);
            for (int j = 0; j < 8; j++) {               // B frag consumed immediately (reg diet)
                bf16x8 b = ldfrag(Bs + (wc * 128 + j * 16 + ln15) * 64 + sw);
                acc[0][j] = __builtin_amdgcn_mfma_f32_16x16x32_bf16(af0, b, acc[0][j], 0, 0, 0);
                acc[1][j] = __builtin_amdgcn_mfma_f32_16x16x32_bf16(af1, b, acc[1][j], 0, 0, 0);
            }
        }
        __syncthreads();
    }
    unsigned short* P = T0p + (size_t)blockIdx.z * B_SZ * RANK;
    for (int i = 0; i < 2; i++)
        for (int j = 0; j < 8; j++) {
            int col = wc * 128 + j * 16 + ln15;
            for (int r = 0; r < 4; r++) {
                int row = tm + wr * 32 + i * 16 + quad * 4 + r;
                P[(size_t)row * RANK + col] = f2bf(acc[i][j][r]);
            }
        }
}

// ---- E: T = bf16( (sum_z T0p[z]) * Schi ) ------------------------------
__global__ void e_red(const unsigned short* __restrict__ T0p, const unsigned short* __restrict__ Schi,
                      unsigned short* __restrict__ T) {
    int i = blockIdx.x * 256 + threadIdx.x;   // ushort8 index
    const size_t stride = (size_t)B_SZ * RANK;
    float a[8] = {};
    for (int z = 0; z < ZSPLIT; z++) {
        ushort8 p = *(const ushort8*)(T0p + z * stride + (size_t)i * 8);
        for (int k = 0; k < 8; k++) a[k] += bf2f(p[k]);
    }
    ushort8 s = *(const ushort8*)(Schi + (size_t)i * 8);
    ushort8 o;
    for (int k = 0; k < 8; k++) o[k] = f2bf(a[k] * bf2f(s[k]));
    *(ushort8*)(T + (size_t)i * 8) = o;
}

// ---- K3: out = relu(T @ V^T + 2*bias) ---------------------------------
// tile 128x128 (m x n), BK=64 (4 iters), grid (32, 32) = 1024 blocks
__launch_bounds__(256, 3)
__global__ void k3_out(const unsigned short* __restrict__ T, const unsigned short* __restrict__ Vb,
                       const float* __restrict__ bias, float* __restrict__ out) {
    __shared__ unsigned short As[128 * 64];
    __shared__ unsigned short Bs[128 * 64];
    int tid = threadIdx.x, w = tid >> 6, lane = tid & 63;
    int ln15 = lane & 15, quad = lane >> 4;
    int wr = w >> 1, wc = w & 1;
    int tn = blockIdx.x * 128, tm = blockIdx.y * 128;
    f32x4 acc[4][4] = {};
    int bl8 = lane >> 3, bcs = lane & 7;
    int bgc = (bcs ^ bl8) * 8;
    for (int kt = 0; kt < RANK / 64; kt++) {
        int k0 = kt * 64;
        for (int c = 0; c < 4; c++) {
            int row = w * 32 + c * 8 + bl8;
            gload_lds16(T + (size_t)(tm + row) * RANK + k0 + bgc, As + row * 64 + bcs * 8);
            gload_lds16(Vb + (size_t)(tn + row) * RANK + k0 + bgc, Bs + row * 64 + bcs * 8);
        }
        __syncthreads();
        for (int kh = 0; kh < 2; kh++) {
            int ch = kh * 4 + quad;
            int sw = (ch ^ (ln15 & 7)) * 8;
            bf16x8 af[4], bfr[4];
            for (int i = 0; i < 4; i++)
                af[i] = ldfrag(As + (wr * 64 + i * 16 + ln15) * 64 + sw);
            for (int j = 0; j < 4; j++)
                bfr[j] = ldfrag(Bs + (wc * 64 + j * 16 + ln15) * 64 + sw);
            for (int i = 0; i < 4; i++)
                for (int j = 0; j < 4; j++)
                    acc[i][j] = __builtin_amdgcn_mfma_f32_16x16x32_bf16(af[i], bfr[j], acc[i][j], 0, 0, 0);
        }
        __syncthreads();
    }
    for (int j = 0; j < 4; j++) {
        int col = tn + wc * 64 + j * 16 + ln15;
        float bv = 2.f * bias[col];
        for (int i = 0; i < 4; i++)
            for (int r = 0; r < 4; r++) {
                int row = tm + wr * 64 + i * 16 + quad * 4 + r;
                float v = acc[i][j][r] + bv;
                out[(size_t)row * UNITS + col] = fmaxf(v, 0.f);
            }
    }
}

extern "C" void kernel_launch(void* const* d_in, const int* in_sizes, int n_in,
                              void* d_out, int out_size, void* d_ws, size_t ws_size,
                              hipStream_t stream) {
    (void)in_sizes; (void)n_in; (void)out_size; (void)ws_size;
    const float* inputs  = (const float*)d_in[0];
    const float* context = (const float*)d_in[1];
    const float* U       = (const float*)d_in[2];
    const float* S       = (const float*)d_in[3];
    const float* V       = (const float*)d_in[4];
    const float* W       = (const float*)d_in[5];
    const float* Bb      = (const float*)d_in[6];
    const float* bias    = (const float*)d_in[7];
    float* out = (float*)d_out;

    char* ws = (char*)d_ws;
    size_t o = 0;
    unsigned short* UT   = (unsigned short*)(ws + o); o += (size_t)RANK * N_IN * 2;
    unsigned short* WT   = (unsigned short*)(ws + o); o += (size_t)RANK * N_CTX * 2;
    unsigned short* Vb   = (unsigned short*)(ws + o); o += (size_t)UNITS * RANK * 2;
    unsigned short* Schi = (unsigned short*)(ws + o); o += (size_t)B_SZ * RANK * 2;
    unsigned short* T    = (unsigned short*)(ws + o); o += (size_t)B_SZ * RANK * 2;
    unsigned short* T0p  = (unsigned short*)(ws + o); o += (size_t)ZSPLIT * B_SZ * RANK * 2;

    prep<<<800, 256, 0, stream>>>(U, W, V, UT, WT, Vb);
    k2_t0<<<dim3(1, B_SZ / 64, ZSPLIT), 256, 0, stream>>>(inputs, UT, T0p);
    k1_chi<<<dim3(RANK / 64, B_SZ / 32), 256, 0, stream>>>(context, WT, S, Bb, Schi);
    e_red<<<(B_SZ * RANK) / (256 * 8), 256, 0, stream>>>(T0p, Schi, T);
    k3_out<<<dim3(UNITS / 128, B_SZ / 128), 256, 0, stream>>>(T, Vb, bias, out);
}

// Round 5
// 175.359 us; speedup vs baseline: 1.1005x; 1.0546x over previous
//
#include <hip/hip_runtime.h>

#define B_SZ 4096
#define N_IN 4096
#define N_CTX 512
#define UNITS 4096
#define RANK 256
#define ZSPLIT 16

typedef __attribute__((ext_vector_type(8))) __bf16 bf16x8;
typedef __attribute__((ext_vector_type(4))) float f32x4;
typedef __attribute__((ext_vector_type(8))) unsigned short ushort8;

// RNE f32->bf16 via native cast: compiler emits v_cvt_pk_bf16_f32 (1 op / 2 elems)
__device__ __forceinline__ unsigned short f2bf(float f) {
    __bf16 h = (__bf16)f;
    return __builtin_bit_cast(unsigned short, h);
}
__device__ __forceinline__ float bf2f(unsigned short h) {
    return __uint_as_float(((unsigned int)h) << 16);
}
__device__ __forceinline__ void gload_lds16(const unsigned short* g, unsigned short* l) {
    __builtin_amdgcn_global_load_lds(
        (const __attribute__((address_space(1))) unsigned int*)g,
        (__attribute__((address_space(3))) unsigned int*)l, 16, 0, 0);
}
__device__ __forceinline__ bf16x8 ldfrag(const unsigned short* p) {
    ushort8 t = *(const ushort8*)p;
    return __builtin_bit_cast(bf16x8, t);
}

// ---- fused prep: U^T (bf16), W^T (bf16), V convert (bf16), one launch ----
__global__ void prep(const float* __restrict__ U, const float* __restrict__ W,
                     const float* __restrict__ V,
                     unsigned short* __restrict__ UT, unsigned short* __restrict__ WT,
                     unsigned short* __restrict__ Vb) {
    __shared__ unsigned short t[64][66];
    int bid = blockIdx.x, tid = threadIdx.x;
    if (bid < 288) {
        const float* src; unsigned short* dst; int R, C, rb, cb;
        if (bid < 256) { src = U; dst = UT; R = N_IN; C = RANK; rb = (bid & 63) * 64; cb = (bid >> 6) * 64; }
        else { int b = bid - 256; src = W; dst = WT; R = N_CTX; C = RANK; rb = (b & 7) * 64; cb = (b >> 3) * 64; }
        int r = tid >> 4, c4 = (tid & 15) * 4;
        for (int i = 0; i < 4; i++) {
            float4 v = *(const float4*)(src + (size_t)(rb + r + i * 16) * C + cb + c4);
            t[r + i * 16][c4 + 0] = f2bf(v.x);
            t[r + i * 16][c4 + 1] = f2bf(v.y);
            t[r + i * 16][c4 + 2] = f2bf(v.z);
            t[r + i * 16][c4 + 3] = f2bf(v.w);
        }
        __syncthreads();
        int c = tid >> 3, r8 = (tid & 7) * 8;
        for (int j = 0; j < 2; j++) {
            int cc = c + j * 32;
            ushort8 o;
            for (int k = 0; k < 8; k++) o[k] = t[r8 + k][cc];
            *(ushort8*)(dst + (size_t)(cb + cc) * R + rb + r8) = o;
        }
    } else {
        size_t base = (size_t)(bid - 288) * 2048 + (size_t)tid * 8;
        float4 a = *(const float4*)(V + base);
        float4 b = *(const float4*)(V + base + 4);
        ushort8 o = { f2bf(a.x), f2bf(a.y), f2bf(a.z), f2bf(a.w),
                      f2bf(b.x), f2bf(b.y), f2bf(b.z), f2bf(b.w) };
        *(ushort8*)(Vb + base) = o;
    }
}

// All GEMM tiles: rows of 64 bf16 = 128B = 8 chunks of 16B.
// LDS slot (row, cs) holds data chunk cs^(row&7)  -> bank-balanced b128 access.

// ---- K1: Schi = S * sigmoid(context@W + B), bf16 out ------------------
// tile 32x64, BK=64, grid (4,128) = 512 blocks
__launch_bounds__(256, 4)
__global__ void k1_chi(const float* __restrict__ ctx, const unsigned short* __restrict__ WT,
                       const float* __restrict__ S, const float* __restrict__ Bb,
                       unsigned short* __restrict__ Schi) {
    __shared__ unsigned short As[32 * 64];
    __shared__ unsigned short Bs[64 * 64];
    int tid = threadIdx.x, w = tid >> 6, lane = tid & 63;
    int ln15 = lane & 15, quad = lane >> 4;
    int wr = w >> 1, wc = w & 1;
    int tm = blockIdx.y * 32, tn = blockIdx.x * 64;
    f32x4 acc2[2] = {};
    int arow = tid >> 3, acs = tid & 7;                 // A: 1 chunk/thread
    const float* ag = ctx + (size_t)(tm + arow) * N_CTX + acs * 8;
    unsigned short* al = As + arow * 64 + (acs ^ (arow & 7)) * 8;
    int bl8 = lane >> 3, bcs = lane & 7;
    int bgc = (bcs ^ bl8) * 8;                          // swizzled global chunk for B
    for (int kt = 0; kt < 8; kt++) {
        int k0 = kt * 64;
        for (int c = 0; c < 2; c++) {
            int row = w * 16 + c * 8 + bl8;
            gload_lds16(WT + (size_t)(tn + row) * N_CTX + k0 + bgc, Bs + row * 64 + bcs * 8);
        }
        {
            float4 v0 = *(const float4*)(ag + k0);
            float4 v1 = *(const float4*)(ag + k0 + 4);
            ushort8 a8 = { f2bf(v0.x), f2bf(v0.y), f2bf(v0.z), f2bf(v0.w),
                           f2bf(v1.x), f2bf(v1.y), f2bf(v1.z), f2bf(v1.w) };
            *(ushort8*)al = a8;
        }
        __syncthreads();
        for (int kh = 0; kh < 2; kh++) {
            int ch = kh * 4 + quad;
            bf16x8 af = ldfrag(As + (wr * 16 + ln15) * 64 + (ch ^ (ln15 & 7)) * 8);
            for (int j = 0; j < 2; j++) {
                int row = wc * 32 + j * 16 + ln15;
                bf16x8 bfr = ldfrag(Bs + row * 64 + (ch ^ (ln15 & 7)) * 8);
                acc2[j] = __builtin_amdgcn_mfma_f32_16x16x32_bf16(af, bfr, acc2[j], 0, 0, 0);
            }
        }
        __syncthreads();
    }
    for (int j = 0; j < 2; j++) {
        int col = tn + wc * 32 + j * 16 + ln15;
        float sv = S[col], bv = Bb[col];
        for (int r = 0; r < 4; r++) {
            int row = tm + wr * 16 + quad * 4 + r;
            float x = acc2[j][r] + bv;
            float chi = sv / (1.f + __expf(-x));
            Schi[(size_t)row * RANK + col] = f2bf(chi);
        }
    }
}

// ---- K2: T0p[z] = inputs@U partial (split-K, bf16 partials) -----------
// tile 128x256 (full RANK), 512 threads (2x4 waves), BK=64, K-slice 256 (4 steps),
// grid (1, 32, 16) = 512 blocks (2 blocks/CU), 48KB LDS single-buffer.
// Epilogue staged through LDS -> coalesced ushort8 stores (vmem-issue diet).
__launch_bounds__(512, 2)
__global__ void k2_t0(const float* __restrict__ X, const unsigned short* __restrict__ UT,
                      unsigned short* __restrict__ T0p) {
    __shared__ char smem[49152];
    unsigned short* As = (unsigned short*)smem;          // 128*64 = 16KB
    unsigned short* Bs = As + 128 * 64;                  // 256*64 = 32KB
    int tid = threadIdx.x, w = tid >> 6, lane = tid & 63;
    int ln15 = lane & 15, quad = lane >> 4;
    int wr = w >> 2, wc = w & 3;                         // 2 x 4 wave grid
    int tm = blockIdx.y * 128;
    int kbase = blockIdx.z * (N_IN / ZSPLIT);
    f32x4 acc[4][4] = {};
    int arow = tid >> 2, acs0 = (tid & 3) * 2;           // A: 2 chunks/thread (16 f32)
    const float* ag = X + (size_t)(tm + arow) * N_IN + kbase + acs0 * 8;
    unsigned short* al0 = As + arow * 64 + ((acs0 + 0) ^ (arow & 7)) * 8;
    unsigned short* al1 = As + arow * 64 + ((acs0 + 1) ^ (arow & 7)) * 8;
    int bl8 = lane >> 3, bcs = lane & 7;
    int bgc = (bcs ^ bl8) * 8;
    for (int kt = 0; kt < (N_IN / ZSPLIT) / 64; kt++) {
        int k0 = kt * 64;
        for (int c = 0; c < 4; c++) {
            int row = w * 32 + c * 8 + bl8;              // rows 0..255 = full RANK
            gload_lds16(UT + (size_t)row * N_IN + kbase + k0 + bgc, Bs + row * 64 + bcs * 8);
        }
        {
            float4 v0 = *(const float4*)(ag + k0);
            float4 v1 = *(const float4*)(ag + k0 + 4);
            float4 u0 = *(const float4*)(ag + k0 + 8);
            float4 u1 = *(const float4*)(ag + k0 + 12);
            ushort8 a8 = { f2bf(v0.x), f2bf(v0.y), f2bf(v0.z), f2bf(v0.w),
                           f2bf(v1.x), f2bf(v1.y), f2bf(v1.z), f2bf(v1.w) };
            ushort8 b8 = { f2bf(u0.x), f2bf(u0.y), f2bf(u0.z), f2bf(u0.w),
                           f2bf(u1.x), f2bf(u1.y), f2bf(u1.z), f2bf(u1.w) };
            *(ushort8*)al0 = a8;
            *(ushort8*)al1 = b8;
        }
        __syncthreads();
        for (int kh = 0; kh < 2; kh++) {
            int ch = kh * 4 + quad;
            int sw = (ch ^ (ln15 & 7)) * 8;
            bf16x8 af[4];
            for (int i = 0; i < 4; i++)
                af[i] = ldfrag(As + (wr * 64 + i * 16 + ln15) * 64 + sw);
            for (int j = 0; j < 4; j++) {
                bf16x8 b = ldfrag(Bs + (wc * 64 + j * 16 + ln15) * 64 + sw);
                for (int i = 0; i < 4; i++)
                    acc[i][j] = __builtin_amdgcn_mfma_f32_16x16x32_bf16(af[i], b, acc[i][j], 0, 0, 0);
            }
        }
        __syncthreads();
    }
    // epilogue: stage 64-row halves through LDS, store coalesced ushort8
    unsigned short* P = T0p + (size_t)blockIdx.z * B_SZ * RANK;
    unsigned short* ep = (unsigned short*)smem;
    const int EPW = 280;                                 // row stride (16B-aligned, bank-spread)
    int er = tid >> 3, ec0 = tid & 7;
    for (int h = 0; h < 2; h++) {
        if (wr == h) {
            for (int i = 0; i < 4; i++)
                for (int j = 0; j < 4; j++)
                    for (int r = 0; r < 4; r++)
                        ep[(i * 16 + quad * 4 + r) * EPW + wc * 64 + j * 16 + ln15] = f2bf(acc[i][j][r]);
        }
        __syncthreads();
        for (int k = 0; k < 4; k++) {
            int chunk = ec0 + 8 * k;
            *(ushort8*)(P + (size_t)(tm + h * 64 + er) * RANK + chunk * 8) =
                *(const ushort8*)(ep + er * EPW + chunk * 8);
        }
        __syncthreads();
    }
}

// ---- E: T = bf16( (sum_z T0p[z]) * Schi ) ------------------------------
__global__ void e_red(const unsigned short* __restrict__ T0p, const unsigned short* __restrict__ Schi,
                      unsigned short* __restrict__ T) {
    int i = blockIdx.x * 256 + threadIdx.x;   // ushort8 index
    const size_t stride = (size_t)B_SZ * RANK;
    float a[8] = {};
    for (int z = 0; z < ZSPLIT; z++) {
        ushort8 p = *(const ushort8*)(T0p + z * stride + (size_t)i * 8);
        for (int k = 0; k < 8; k++) a[k] += bf2f(p[k]);
    }
    ushort8 s = *(const ushort8*)(Schi + (size_t)i * 8);
    ushort8 o;
    for (int k = 0; k < 8; k++) o[k] = f2bf(a[k] * bf2f(s[k]));
    *(ushort8*)(T + (size_t)i * 8) = o;
}

// ---- K3: out = relu(T @ V^T + 2*bias) ---------------------------------
// tile 128x128 (m x n), BK=64 (4 iters), grid (32, 32) = 1024 blocks.
// Epilogue staged through LDS -> coalesced float4 stores (vmem-issue diet).
__launch_bounds__(256, 3)
__global__ void k3_out(const unsigned short* __restrict__ T, const unsigned short* __restrict__ Vb,
                       const float* __restrict__ bias, float* __restrict__ out) {
    __shared__ char smem[34816];                         // max(32KB tiles, 64x136 f32 epilogue)
    unsigned short* As = (unsigned short*)smem;          // 128*64
    unsigned short* Bs = As + 128 * 64;                  // 128*64
    int tid = threadIdx.x, w = tid >> 6, lane = tid & 63;
    int ln15 = lane & 15, quad = lane >> 4;
    int wr = w >> 1, wc = w & 1;
    int tn = blockIdx.x * 128, tm = blockIdx.y * 128;
    f32x4 acc[4][4] = {};
    int bl8 = lane >> 3, bcs = lane & 7;
    int bgc = (bcs ^ bl8) * 8;
    for (int kt = 0; kt < RANK / 64; kt++) {
        int k0 = kt * 64;
        for (int c = 0; c < 4; c++) {
            int row = w * 32 + c * 8 + bl8;
            gload_lds16(T + (size_t)(tm + row) * RANK + k0 + bgc, As + row * 64 + bcs * 8);
            gload_lds16(Vb + (size_t)(tn + row) * RANK + k0 + bgc, Bs + row * 64 + bcs * 8);
        }
        __syncthreads();
        for (int kh = 0; kh < 2; kh++) {
            int ch = kh * 4 + quad;
            int sw = (ch ^ (ln15 & 7)) * 8;
            bf16x8 af[4], bfr[4];
            for (int i = 0; i < 4; i++)
                af[i] = ldfrag(As + (wr * 64 + i * 16 + ln15) * 64 + sw);
            for (int j = 0; j < 4; j++)
                bfr[j] = ldfrag(Bs + (wc * 64 + j * 16 + ln15) * 64 + sw);
            for (int i = 0; i < 4; i++)
                for (int j = 0; j < 4; j++)
                    acc[i][j] = __builtin_amdgcn_mfma_f32_16x16x32_bf16(af[i], bfr[j], acc[i][j], 0, 0, 0);
        }
        __syncthreads();
    }
    // bias + relu in registers, then LDS-staged coalesced float4 stores
    float* ep = (float*)smem;
    const int EPW = 136;                                 // f32 row stride (16B-aligned)
    int er = tid >> 2, ec0 = tid & 3;
    for (int h = 0; h < 2; h++) {
        if (wr == h) {
            for (int j = 0; j < 4; j++) {
                int col = wc * 64 + j * 16 + ln15;
                float bv = 2.f * bias[tn + col];
                for (int i = 0; i < 4; i++)
                    for (int r = 0; r < 4; r++)
                        ep[(i * 16 + quad * 4 + r) * EPW + col] = fmaxf(acc[i][j][r] + bv, 0.f);
            }
        }
        __syncthreads();
        for (int k = 0; k < 8; k++) {
            int chunk = ec0 + 4 * k;                     // 32 float4-chunks per row
            *(float4*)(out + (size_t)(tm + h * 64 + er) * UNITS + tn + chunk * 4) =
                *(const float4*)(ep + er * EPW + chunk * 4);
        }
        __syncthreads();
    }
}

extern "C" void kernel_launch(void* const* d_in, const int* in_sizes, int n_in,
                              void* d_out, int out_size, void* d_ws, size_t ws_size,
                              hipStream_t stream) {
    (void)in_sizes; (void)n_in; (void)out_size; (void)ws_size;
    const float* inputs  = (const float*)d_in[0];
    const float* context = (const float*)d_in[1];
    const float* U       = (const float*)d_in[2];
    const float* S       = (const float*)d_in[3];
    const float* V       = (const float*)d_in[4];
    const float* W       = (const float*)d_in[5];
    const float* Bb      = (const float*)d_in[6];
    const float* bias    = (const float*)d_in[7];
    float* out = (float*)d_out;

    char* ws = (char*)d_ws;
    size_t o = 0;
    unsigned short* UT   = (unsigned short*)(ws + o); o += (size_t)RANK * N_IN * 2;
    unsigned short* WT   = (unsigned short*)(ws + o); o += (size_t)RANK * N_CTX * 2;
    unsigned short* Vb   = (unsigned short*)(ws + o); o += (size_t)UNITS * RANK * 2;
    unsigned short* Schi = (unsigned short*)(ws + o); o += (size_t)B_SZ * RANK * 2;
    unsigned short* T    = (unsigned short*)(ws + o); o += (size_t)B_SZ * RANK * 2;
    unsigned short* T0p  = (unsigned short*)(ws + o); o += (size_t)ZSPLIT * B_SZ * RANK * 2;

    prep<<<800, 256, 0, stream>>>(U, W, V, UT, WT, Vb);
    k2_t0<<<dim3(1, B_SZ / 128, ZSPLIT), 512, 0, stream>>>(inputs, UT, T0p);
    k1_chi<<<dim3(RANK / 64, B_SZ / 32), 256, 0, stream>>>(context, WT, S, Bb, Schi);
    e_red<<<(B_SZ * RANK) / (256 * 8), 256, 0, stream>>>(T0p, Schi, T);
    k3_out<<<dim3(UNITS / 128, B_SZ / 128), 256, 0, stream>>>(T, Vb, bias, out);
}

// Round 6
// 175.004 us; speedup vs baseline: 1.1028x; 1.0020x over previous
//
#include <hip/hip_runtime.h>

#define B_SZ 4096
#define N_IN 4096
#define N_CTX 512
#define UNITS 4096
#define RANK 256
#define ZSPLIT 16

typedef __attribute__((ext_vector_type(8))) __bf16 bf16x8;
typedef __attribute__((ext_vector_type(4))) float f32x4;
typedef __attribute__((ext_vector_type(8))) unsigned short ushort8;

// RNE f32->bf16 via native cast: compiler emits v_cvt_pk_bf16_f32 (1 op / 2 elems)
__device__ __forceinline__ unsigned short f2bf(float f) {
    __bf16 h = (__bf16)f;
    return __builtin_bit_cast(unsigned short, h);
}
__device__ __forceinline__ float bf2f(unsigned short h) {
    return __uint_as_float(((unsigned int)h) << 16);
}
__device__ __forceinline__ void gload_lds16(const unsigned short* g, unsigned short* l) {
    __builtin_amdgcn_global_load_lds(
        (const __attribute__((address_space(1))) unsigned int*)g,
        (__attribute__((address_space(3))) unsigned int*)l, 16, 0, 0);
}
__device__ __forceinline__ bf16x8 ldfrag(const unsigned short* p) {
    ushort8 t = *(const ushort8*)p;
    return __builtin_bit_cast(bf16x8, t);
}

// ---- fused prep: U^T (bf16), W^T (bf16), V convert (bf16), one launch ----
__global__ void prep(const float* __restrict__ U, const float* __restrict__ W,
                     const float* __restrict__ V,
                     unsigned short* __restrict__ UT, unsigned short* __restrict__ WT,
                     unsigned short* __restrict__ Vb) {
    __shared__ unsigned short t[64][66];
    int bid = blockIdx.x, tid = threadIdx.x;
    if (bid < 288) {
        const float* src; unsigned short* dst; int R, C, rb, cb;
        if (bid < 256) { src = U; dst = UT; R = N_IN; C = RANK; rb = (bid & 63) * 64; cb = (bid >> 6) * 64; }
        else { int b = bid - 256; src = W; dst = WT; R = N_CTX; C = RANK; rb = (b & 7) * 64; cb = (b >> 3) * 64; }
        int r = tid >> 4, c4 = (tid & 15) * 4;
        for (int i = 0; i < 4; i++) {
            float4 v = *(const float4*)(src + (size_t)(rb + r + i * 16) * C + cb + c4);
            t[r + i * 16][c4 + 0] = f2bf(v.x);
            t[r + i * 16][c4 + 1] = f2bf(v.y);
            t[r + i * 16][c4 + 2] = f2bf(v.z);
            t[r + i * 16][c4 + 3] = f2bf(v.w);
        }
        __syncthreads();
        int c = tid >> 3, r8 = (tid & 7) * 8;
        for (int j = 0; j < 2; j++) {
            int cc = c + j * 32;
            ushort8 o;
            for (int k = 0; k < 8; k++) o[k] = t[r8 + k][cc];
            *(ushort8*)(dst + (size_t)(cb + cc) * R + rb + r8) = o;
        }
    } else {
        size_t base = (size_t)(bid - 288) * 2048 + (size_t)tid * 8;
        float4 a = *(const float4*)(V + base);
        float4 b = *(const float4*)(V + base + 4);
        ushort8 o = { f2bf(a.x), f2bf(a.y), f2bf(a.z), f2bf(a.w),
                      f2bf(b.x), f2bf(b.y), f2bf(b.z), f2bf(b.w) };
        *(ushort8*)(Vb + base) = o;
    }
}

// All GEMM tiles: rows of 64 bf16 = 128B = 8 chunks of 16B.
// LDS slot (row, cs) holds data chunk cs^(row&7)  -> bank-balanced b128 access.

// ---- K21: fused launch. blocks 0..511: k2 (T0p partials); 512..767: 2x k1 tiles ----
// k2: tile 128x256 (full RANK), 512 thr (2x4 waves), BK=64, K-slice 256,
//     grid-part 512 blocks (2/CU), 48KB LDS, LDS-staged ushort8 epilogue.
// k1: Schi = S*sigmoid(ctx@W+B); two independent 32x64 tiles per block
//     (both halves run the identical 8-step loop -> __syncthreads aligns).
__launch_bounds__(512, 2)
__global__ void k21(const float* __restrict__ X, const unsigned short* __restrict__ UT,
                    unsigned short* __restrict__ T0p,
                    const float* __restrict__ ctx, const unsigned short* __restrict__ WT,
                    const float* __restrict__ S, const float* __restrict__ Bb,
                    unsigned short* __restrict__ Schi) {
    __shared__ char smem[49152];
    int tid = threadIdx.x, bfull = blockIdx.x;
    int w = tid >> 6, lane = tid & 63;
    int ln15 = lane & 15, quad = lane >> 4;
    if (bfull < 512) {
        // ---------------- k2 ----------------
        int z = bfull >> 5, my = bfull & 31;
        unsigned short* As = (unsigned short*)smem;          // 128*64 = 16KB
        unsigned short* Bs = As + 128 * 64;                  // 256*64 = 32KB
        int wr = w >> 2, wc = w & 3;                         // 2 x 4 wave grid
        int tm = my * 128;
        int kbase = z * (N_IN / ZSPLIT);
        f32x4 acc[4][4] = {};
        int arow = tid >> 2, acs0 = (tid & 3) * 2;           // A: 2 chunks/thread (16 f32)
        const float* ag = X + (size_t)(tm + arow) * N_IN + kbase + acs0 * 8;
        unsigned short* al0 = As + arow * 64 + ((acs0 + 0) ^ (arow & 7)) * 8;
        unsigned short* al1 = As + arow * 64 + ((acs0 + 1) ^ (arow & 7)) * 8;
        int bl8 = lane >> 3, bcs = lane & 7;
        int bgc = (bcs ^ bl8) * 8;
        for (int kt = 0; kt < (N_IN / ZSPLIT) / 64; kt++) {
            int k0 = kt * 64;
            for (int c = 0; c < 4; c++) {
                int row = w * 32 + c * 8 + bl8;              // rows 0..255 = full RANK
                gload_lds16(UT + (size_t)row * N_IN + kbase + k0 + bgc, Bs + row * 64 + bcs * 8);
            }
            {
                float4 v0 = *(const float4*)(ag + k0);
                float4 v1 = *(const float4*)(ag + k0 + 4);
                float4 u0 = *(const float4*)(ag + k0 + 8);
                float4 u1 = *(const float4*)(ag + k0 + 12);
                ushort8 a8 = { f2bf(v0.x), f2bf(v0.y), f2bf(v0.z), f2bf(v0.w),
                               f2bf(v1.x), f2bf(v1.y), f2bf(v1.z), f2bf(v1.w) };
                ushort8 b8 = { f2bf(u0.x), f2bf(u0.y), f2bf(u0.z), f2bf(u0.w),
                               f2bf(u1.x), f2bf(u1.y), f2bf(u1.z), f2bf(u1.w) };
                *(ushort8*)al0 = a8;
                *(ushort8*)al1 = b8;
            }
            __syncthreads();
            for (int kh = 0; kh < 2; kh++) {
                int ch = kh * 4 + quad;
                int sw = (ch ^ (ln15 & 7)) * 8;
                bf16x8 af[4];
                for (int i = 0; i < 4; i++)
                    af[i] = ldfrag(As + (wr * 64 + i * 16 + ln15) * 64 + sw);
                for (int j = 0; j < 4; j++) {
                    bf16x8 b = ldfrag(Bs + (wc * 64 + j * 16 + ln15) * 64 + sw);
                    for (int i = 0; i < 4; i++)
                        acc[i][j] = __builtin_amdgcn_mfma_f32_16x16x32_bf16(af[i], b, acc[i][j], 0, 0, 0);
                }
            }
            __syncthreads();
        }
        // epilogue: stage 64-row halves through LDS, store coalesced ushort8
        unsigned short* P = T0p + (size_t)z * B_SZ * RANK;
        unsigned short* ep = (unsigned short*)smem;
        const int EPW = 280;                                 // row stride (16B-aligned, bank-spread)
        int er = tid >> 3, ec0 = tid & 7;
        for (int h = 0; h < 2; h++) {
            if (wr == h) {
                for (int i = 0; i < 4; i++)
                    for (int j = 0; j < 4; j++)
                        for (int r = 0; r < 4; r++)
                            ep[(i * 16 + quad * 4 + r) * EPW + wc * 64 + j * 16 + ln15] = f2bf(acc[i][j][r]);
            }
            __syncthreads();
            for (int k = 0; k < 4; k++) {
                int chunk = ec0 + 8 * k;
                *(ushort8*)(P + (size_t)(tm + h * 64 + er) * RANK + chunk * 8) =
                    *(const ushort8*)(ep + er * EPW + chunk * 8);
            }
            __syncthreads();
        }
    } else {
        // ---------------- k1 (two 32x64 tiles per block) ----------------
        int hh = tid >> 8;                                   // half 0/1
        int sb = (bfull - 512) * 2 + hh;                     // original k1 block id (0..511)
        int bx = sb & 3, by = sb >> 2;
        int t = tid & 255;
        int lw = t >> 6, llane = t & 63;
        int lln15 = llane & 15, lquad = llane >> 4;
        int wr = lw >> 1, wc = lw & 1;
        unsigned short* base = (unsigned short*)smem + hh * 6144;
        unsigned short* As = base;                           // 32*64
        unsigned short* Bs = base + 32 * 64;                 // 64*64
        int tm = by * 32, tn = bx * 64;
        f32x4 acc2[2] = {};
        int arow = t >> 3, acs = t & 7;                      // A: 1 chunk/thread
        const float* ag = ctx + (size_t)(tm + arow) * N_CTX + acs * 8;
        unsigned short* al = As + arow * 64 + (acs ^ (arow & 7)) * 8;
        int bl8 = llane >> 3, bcs = llane & 7;
        int bgc = (bcs ^ bl8) * 8;
        for (int kt = 0; kt < 8; kt++) {
            int k0 = kt * 64;
            for (int c = 0; c < 2; c++) {
                int row = lw * 16 + c * 8 + bl8;
                gload_lds16(WT + (size_t)(tn + row) * N_CTX + k0 + bgc, Bs + row * 64 + bcs * 8);
            }
            {
                float4 v0 = *(const float4*)(ag + k0);
                float4 v1 = *(const float4*)(ag + k0 + 4);
                ushort8 a8 = { f2bf(v0.x), f2bf(v0.y), f2bf(v0.z), f2bf(v0.w),
                               f2bf(v1.x), f2bf(v1.y), f2bf(v1.z), f2bf(v1.w) };
                *(ushort8*)al = a8;
            }
            __syncthreads();
            for (int kh = 0; kh < 2; kh++) {
                int ch = kh * 4 + lquad;
                bf16x8 af = ldfrag(As + (wr * 16 + lln15) * 64 + (ch ^ (lln15 & 7)) * 8);
                for (int j = 0; j < 2; j++) {
                    int row = wc * 32 + j * 16 + lln15;
                    bf16x8 bfr = ldfrag(Bs + row * 64 + (ch ^ (lln15 & 7)) * 8);
                    acc2[j] = __builtin_amdgcn_mfma_f32_16x16x32_bf16(af, bfr, acc2[j], 0, 0, 0);
                }
            }
            __syncthreads();
        }
        for (int j = 0; j < 2; j++) {
            int col = tn + wc * 32 + j * 16 + lln15;
            float sv = S[col], bv = Bb[col];
            for (int r = 0; r < 4; r++) {
                int row = tm + wr * 16 + lquad * 4 + r;
                float x = acc2[j][r] + bv;
                float chi = sv / (1.f + __expf(-x));
                Schi[(size_t)row * RANK + col] = f2bf(chi);
            }
        }
    }
}

// ---- E: T = bf16( (sum_z T0p[z]) * Schi ) ------------------------------
__global__ void e_red(const unsigned short* __restrict__ T0p, const unsigned short* __restrict__ Schi,
                      unsigned short* __restrict__ T) {
    int i = blockIdx.x * 256 + threadIdx.x;   // ushort8 index
    const size_t stride = (size_t)B_SZ * RANK;
    float a[8] = {};
    for (int z = 0; z < ZSPLIT; z++) {
        ushort8 p = *(const ushort8*)(T0p + z * stride + (size_t)i * 8);
        for (int k = 0; k < 8; k++) a[k] += bf2f(p[k]);
    }
    ushort8 s = *(const ushort8*)(Schi + (size_t)i * 8);
    ushort8 o;
    for (int k = 0; k < 8; k++) o[k] = f2bf(a[k] * bf2f(s[k]));
    *(ushort8*)(T + (size_t)i * 8) = o;
}

// ---- K3: out = relu(T @ V^T + 2*bias) ---------------------------------
// tile 128x256 (m x n), 512 thr (2x4 waves), BK=64 (4 iters),
// grid (16, 32) = 512 blocks (2/CU). LDS-staged float4 epilogue (64-row halves).
__launch_bounds__(512, 2)
__global__ void k3_out(const unsigned short* __restrict__ T, const unsigned short* __restrict__ Vb,
                       const float* __restrict__ bias, float* __restrict__ out) {
    __shared__ char smem[66560];                         // loop: 48KB tiles; epi: 64x260 f32
    unsigned short* As = (unsigned short*)smem;          // 128*64 = 16KB
    unsigned short* Bs = As + 128 * 64;                  // 256*64 = 32KB
    int tid = threadIdx.x, w = tid >> 6, lane = tid & 63;
    int ln15 = lane & 15, quad = lane >> 4;
    int wr = w >> 2, wc = w & 3;                         // 2 x 4 wave grid
    int tn = blockIdx.x * 256, tm = blockIdx.y * 128;
    f32x4 acc[4][4] = {};
    int bl8 = lane >> 3, bcs = lane & 7;
    int bgc = (bcs ^ bl8) * 8;
    for (int kt = 0; kt < RANK / 64; kt++) {
        int k0 = kt * 64;
        for (int c = 0; c < 2; c++) {                    // A: 128 rows, 2 chunks/thread
            int row = w * 16 + c * 8 + bl8;
            gload_lds16(T + (size_t)(tm + row) * RANK + k0 + bgc, As + row * 64 + bcs * 8);
        }
        for (int c = 0; c < 4; c++) {                    // B: 256 rows, 4 chunks/thread
            int row = w * 32 + c * 8 + bl8;
            gload_lds16(Vb + (size_t)(tn + row) * RANK + k0 + bgc, Bs + row * 64 + bcs * 8);
        }
        __syncthreads();
        for (int kh = 0; kh < 2; kh++) {
            int ch = kh * 4 + quad;
            int sw = (ch ^ (ln15 & 7)) * 8;
            bf16x8 af[4];
            for (int i = 0; i < 4; i++)
                af[i] = ldfrag(As + (wr * 64 + i * 16 + ln15) * 64 + sw);
            for (int j = 0; j < 4; j++) {
                bf16x8 b = ldfrag(Bs + (wc * 64 + j * 16 + ln15) * 64 + sw);
                for (int i = 0; i < 4; i++)
                    acc[i][j] = __builtin_amdgcn_mfma_f32_16x16x32_bf16(af[i], b, acc[i][j], 0, 0, 0);
            }
        }
        __syncthreads();
    }
    // bias + relu in registers, then LDS-staged coalesced float4 stores (64-row halves)
    float* ep = (float*)smem;
    const int EPW = 260;                                 // f32 row stride (16B-aligned, bank-spread)
    int er = tid >> 3, ec0 = tid & 7;
    for (int h = 0; h < 2; h++) {
        if (wr == h) {
            for (int j = 0; j < 4; j++) {
                int col = wc * 64 + j * 16 + ln15;
                float bv = 2.f * bias[tn + col];
                for (int i = 0; i < 4; i++)
                    for (int r = 0; r < 4; r++)
                        ep[(i * 16 + quad * 4 + r) * EPW + col] = fmaxf(acc[i][j][r] + bv, 0.f);
            }
        }
        __syncthreads();
        for (int k = 0; k < 8; k++) {
            int chunk = ec0 + 8 * k;                     // 64 float4-chunks per row
            *(float4*)(out + (size_t)(tm + h * 64 + er) * UNITS + tn + chunk * 4) =
                *(const float4*)(ep + er * EPW + chunk * 4);
        }
        __syncthreads();
    }
}

extern "C" void kernel_launch(void* const* d_in, const int* in_sizes, int n_in,
                              void* d_out, int out_size, void* d_ws, size_t ws_size,
                              hipStream_t stream) {
    (void)in_sizes; (void)n_in; (void)out_size; (void)ws_size;
    const float* inputs  = (const float*)d_in[0];
    const float* context = (const float*)d_in[1];
    const float* U       = (const float*)d_in[2];
    const float* S       = (const float*)d_in[3];
    const float* V       = (const float*)d_in[4];
    const float* W       = (const float*)d_in[5];
    const float* Bb      = (const float*)d_in[6];
    const float* bias    = (const float*)d_in[7];
    float* out = (float*)d_out;

    char* ws = (char*)d_ws;
    size_t o = 0;
    unsigned short* UT   = (unsigned short*)(ws + o); o += (size_t)RANK * N_IN * 2;
    unsigned short* WT   = (unsigned short*)(ws + o); o += (size_t)RANK * N_CTX * 2;
    unsigned short* Vb   = (unsigned short*)(ws + o); o += (size_t)UNITS * RANK * 2;
    unsigned short* Schi = (unsigned short*)(ws + o); o += (size_t)B_SZ * RANK * 2;
    unsigned short* T    = (unsigned short*)(ws + o); o += (size_t)B_SZ * RANK * 2;
    unsigned short* T0p  = (unsigned short*)(ws + o); o += (size_t)ZSPLIT * B_SZ * RANK * 2;

    prep<<<800, 256, 0, stream>>>(U, W, V, UT, WT, Vb);
    k21<<<768, 512, 0, stream>>>(inputs, UT, T0p, context, WT, S, Bb, Schi);
    e_red<<<(B_SZ * RANK) / (256 * 8), 256, 0, stream>>>(T0p, Schi, T);
    k3_out<<<dim3(UNITS / 256, B_SZ / 128), 512, 0, stream>>>(T, Vb, bias, out);
}